// Round 4
// baseline (474.024 us; speedup 1.0000x reference)
//
#include <hip/hip_runtime.h>
#include <stdint.h>

#define Bn 4
#define Cn 256
#define Hn 128
#define Wn 128
#define Nn 16384
#define EPSn 1e-10f

typedef unsigned short u16;
typedef __attribute__((ext_vector_type(8))) short short8;
typedef __attribute__((ext_vector_type(4))) short short4v;
typedef __attribute__((ext_vector_type(4))) float f32x4;

#define GLOAD_LDS16(g, l)                                                        \
    __builtin_amdgcn_global_load_lds(                                            \
        (const __attribute__((address_space(1))) unsigned int*)(const void*)(g), \
        (__attribute__((address_space(3))) unsigned int*)(void*)(l), 16, 0, 0)

__device__ __forceinline__ float bf2f(u16 u) {
    union { float f; uint32_t i; } v; v.i = ((uint32_t)u) << 16; return v.f;
}
__device__ __forceinline__ u16 f2bf(float f) {
    union { float f; uint32_t i; } v; v.f = f;
    uint32_t r = v.i + 0x7FFFu + ((v.i >> 16) & 1u);
    return (u16)(r >> 16);
}
__device__ __forceinline__ float delu_f(float x) {
    return x >= 0.f ? fmaf(10.f, x, 1.f) : __expf(10.f * x);
}

// ---------------- prep: pack all weights into MFMA-fragment order ----------------
// poff = ((kc*4+s)*4+mf)*512 + (lk*16+lr)*8 + j   -> per-(kc,s,mf) contiguous 1KB block
__global__ void prep_kernel(const float* __restrict__ wq1, const float* __restrict__ wk1,
                            const float* __restrict__ wv1,
                            const float* __restrict__ wq2, const float* __restrict__ wk2,
                            const float* __restrict__ wv2,
                            const float* __restrict__ wd1, const float* __restrict__ wd3,
                            const float* __restrict__ bd1, const float* __restrict__ bd3,
                            u16* __restrict__ wq1p, u16* __restrict__ wk1p, u16* __restrict__ wv1p,
                            u16* __restrict__ wq2p, u16* __restrict__ wk2p, u16* __restrict__ wv2p,
                            u16* __restrict__ wallp, float* __restrict__ bfused)
{
    int idx = blockIdx.x * 256 + threadIdx.x;   // o*256 + c
    int o = idx >> 8, c = idx & 255;
    if (idx < 256) bfused[idx] = bd1[idx] + bd3[idx];
    int s = o >> 6, mf = (o >> 4) & 3, lr = o & 15;
    int kc = c >> 5, lk = (c >> 3) & 3, j = c & 7;
    int poff = ((kc * 4 + s) * 4 + mf) * 512 + (lk * 16 + lr) * 8 + j;
    wq1p[poff] = f2bf(wq1[idx]);
    wk1p[poff] = f2bf(wk1[idx]);
    wv1p[poff] = f2bf(wv1[idx]);
    wq2p[poff] = f2bf(wq2[idx]);
    wk2p[poff] = f2bf(wk2[idx]);
    wv2p[poff] = f2bf(wv2[idx]);
    float wd1v = wd1[idx];
    #pragma unroll
    for (int tap = 0; tap < 9; ++tap) {
        float w = wd3[idx * 9 + tap] + (tap == 4 ? wd1v : 0.f);
        wallp[tap * 65536 + poff] = f2bf(w);
    }
}

// ---------------- transpose: x (B,C,N) f32 -> xTt (B, C/8, N, 8ch) bf16 ----------------
__global__ void transpose_kernel(const float* __restrict__ x, u16* __restrict__ xTt)
{
    __shared__ __align__(16) u16 tl[64][72];
    int t = threadIdx.x;
    int n0 = blockIdx.x * 64, c0 = blockIdx.y * 64, b = blockIdx.z;
    int cl = t >> 4, nl = (t & 15) * 4;
    #pragma unroll
    for (int pc = 0; pc < 4; ++pc) {
        int c = pc * 16 + cl;
        float4 v = *(const float4*)&x[((size_t)(b * Cn + c0 + c)) * Nn + n0 + nl];
        tl[nl + 0][c] = f2bf(v.x);
        tl[nl + 1][c] = f2bf(v.y);
        tl[nl + 2][c] = f2bf(v.z);
        tl[nl + 3][c] = f2bf(v.w);
    }
    __syncthreads();
    int cg0 = c0 >> 3;
    #pragma unroll
    for (int ps = 0; ps < 2; ++ps) {
        int id = ps * 256 + t;
        int cgl = id >> 6, n = id & 63;
        short8 v = *(const short8*)&tl[n][cgl * 8];
        *(short8*)&xTt[(((size_t)(b * 32 + cg0 + cgl)) * Nn + n0 + n) * 8] = v;
    }
}

// ---------------- fused Q+K+V projection GEMM ----------------
// LDS: [4 lk][130 px][8 ch] u16 per buffer (conflict-free fragment reads)
#define QBUF (4 * 130 * 8)

__global__ __launch_bounds__(256, 2) void qkv_kernel(
    const u16* __restrict__ xTt,
    const u16* __restrict__ wqp, const u16* __restrict__ wkp, const u16* __restrict__ wvp,
    const float* __restrict__ bq, const float* __restrict__ bk, const float* __restrict__ bv,
    u16* __restrict__ kout, u16* __restrict__ kvout, float* __restrict__ qsum)
{
    __shared__ __align__(16) u16 Bt[2 * QBUF];
    int t = threadIdx.x;
    int nb = blockIdx.x, mb = blockIdx.y, b = blockIdx.z;
    int lane = t & 63, wid = t >> 6;
    int wm = wid >> 1, wn = wid & 1;
    int lr = lane & 15, lk = lane >> 4;
    int s = mb * 2 + wm;

    f32x4 zf = {0.f, 0.f, 0.f, 0.f};
    f32x4 accq[4][4], acck[4][4], accv[4][4];
    #pragma unroll
    for (int i = 0; i < 4; ++i)
        #pragma unroll
        for (int j = 0; j < 4; ++j) { accq[i][j] = zf; acck[i][j] = zf; accv[i][j] = zf; }

    auto STAGE = [&](int bufi, int kc) {
        #pragma unroll
        for (int i = 0; i < 2; ++i) {
            int run = wid * 2 + i;            // 0..7 = lk(4) x seg(2)
            int slk = run >> 1, seg = run & 1;
            const u16* g = xTt + (((size_t)(b * 32 + kc * 4 + slk)) * Nn
                                  + nb * 128 + seg * 64 + lane) * 8;
            GLOAD_LDS16(g, &Bt[bufi * QBUF + (slk * 130 + seg * 64) * 8]);
        }
    };

    STAGE(0, 0);
    __syncthreads();

    #pragma unroll 2
    for (int kc = 0; kc < 8; ++kc) {
        int cur = kc & 1;
        if (kc < 7) STAGE(cur ^ 1, kc + 1);
        int abase = ((kc * 4 + s) * 4) * 512 + lane * 8;
        short8 bf[4];
        #pragma unroll
        for (int nf = 0; nf < 4; ++nf)
            bf[nf] = *(const short8*)&Bt[cur * QBUF + (lk * 130 + wn * 64 + nf * 16 + lr) * 8];
        #pragma unroll
        for (int mf = 0; mf < 4; ++mf) {
            short8 aq = *(const short8*)&wqp[abase + mf * 512];
            short8 ak = *(const short8*)&wkp[abase + mf * 512];
            short8 av = *(const short8*)&wvp[abase + mf * 512];
            #pragma unroll
            for (int nf = 0; nf < 4; ++nf) {
                accq[mf][nf] = __builtin_amdgcn_mfma_f32_16x16x32_bf16(aq, bf[nf], accq[mf][nf], 0, 0, 0);
                acck[mf][nf] = __builtin_amdgcn_mfma_f32_16x16x32_bf16(ak, bf[nf], acck[mf][nf], 0, 0, 0);
                accv[mf][nf] = __builtin_amdgcn_mfma_f32_16x16x32_bf16(av, bf[nf], accv[mf][nf], 0, 0, 0);
            }
        }
        __syncthreads();
    }

    float qs[4] = {0.f, 0.f, 0.f, 0.f};
    #pragma unroll
    for (int mf = 0; mf < 4; ++mf) {
        #pragma unroll
        for (int r = 0; r < 4; ++r) {
            int o = mb * 128 + wm * 64 + mf * 16 + lk * 4 + r;
            float bqv = bq[o], bkv = bk[o], bvv = bv[o];
            #pragma unroll
            for (int nf = 0; nf < 4; ++nf) {
                int n = nb * 128 + wn * 64 + nf * 16 + lr;
                size_t idx = ((size_t)(b * Cn + o)) * Nn + n;
                float qv = delu_f(accq[mf][nf][r] + bqv);
                qs[nf] += qv;
                float kk = delu_f(acck[mf][nf][r] + bkv);
                kout[idx] = f2bf(kk);
                float vv = accv[mf][nf][r] + bvv;
                kvout[idx] = f2bf(kk * vv);
            }
        }
    }
    #pragma unroll
    for (int nf = 0; nf < 4; ++nf) {
        float sgl = qs[nf];
        sgl += __shfl_xor(sgl, 16);
        sgl += __shfl_xor(sgl, 32);
        if (lk == 0)
            atomicAdd(&qsum[b * Nn + nb * 128 + wn * 64 + nf * 16 + lr], sgl);
    }
}

// ---------------- esum[b,c] = sum_n k[b,c,n] * qsum[b,n] ----------------
__global__ void esum_kernel(const u16* __restrict__ k, const float* __restrict__ qsum,
                            float* __restrict__ esum)
{
    int c = blockIdx.x, b = blockIdx.y, t = threadIdx.x;
    const u16* kr = k + ((size_t)(b * Cn + c)) * Nn;
    const float* qr = qsum + b * Nn;
    float s = 0.f;
    for (int i = t * 8; i < Nn; i += 2048) {
        short8 kv = *(const short8*)&kr[i];
        #pragma unroll
        for (int j = 0; j < 8; ++j) s = fmaf(bf2f((u16)kv[j]), qr[i + j], s);
    }
    #pragma unroll
    for (int m = 32; m; m >>= 1) s += __shfl_xor(s, m);
    __shared__ float red[4];
    if ((t & 63) == 0) red[t >> 6] = s;
    __syncthreads();
    if (t == 0) esum[b * Cn + c] = red[0] + red[1] + red[2] + red[3];
}

// ---------------- norm[b,n] = 1/(sum_c esum[b,c]*k[b,c,n] + eps) ----------------
__global__ void norm_kernel(const u16* __restrict__ k, const float* __restrict__ esum,
                            float* __restrict__ nrm)
{
    __shared__ float es[256];
    int t = threadIdx.x, b = blockIdx.y;
    es[t] = esum[b * Cn + t];
    __syncthreads();
    int n0 = blockIdx.x * 1024 + t * 4;
    float a0 = 0.f, a1 = 0.f, a2 = 0.f, a3 = 0.f;
    const u16* kb = k + (size_t)b * Cn * Nn + n0;
    #pragma unroll 4
    for (int c = 0; c < 256; ++c) {
        short4v kv = *(const short4v*)&kb[(size_t)c * Nn];
        float e = es[c];
        a0 = fmaf(e, bf2f((u16)kv[0]), a0);
        a1 = fmaf(e, bf2f((u16)kv[1]), a1);
        a2 = fmaf(e, bf2f((u16)kv[2]), a2);
        a3 = fmaf(e, bf2f((u16)kv[3]), a3);
    }
    float* nb = nrm + b * Nn + n0;
    nb[0] = 1.f / (a0 + EPSn);
    nb[1] = 1.f / (a1 + EPSn);
    nb[2] = 1.f / (a2 + EPSn);
    nb[3] = 1.f / (a3 + EPSn);
}

// ---------------- pass 2: halo-GEMM conv3x3(+1x1) + att + residual ----------------
// LDS halo per k-chunk: [4 hy x 4 lk rows][130 px][8 ch] u16, double buffered.
#define BSZc (16 * 130 * 8)           // 16640 u16 per buffer

__global__ __launch_bounds__(256, 2) void conv_att_kernel(
    const float* __restrict__ x, const u16* __restrict__ xTt,
    const u16* __restrict__ wallp, const float* __restrict__ bfused,
    const u16* __restrict__ kv, const float* __restrict__ esum,
    const float* __restrict__ nrm, const float* __restrict__ gamma,
    float* __restrict__ out)
{
    __shared__ __align__(16) u16 Bl[2 * BSZc];   // 66,560 B
    int t = threadIdx.x;
    int mb = blockIdx.x, yp = blockIdx.y, b = blockIdx.z;
    int ybase = yp * 2;
    int lane = t & 63, wid = t >> 6;
    int wm = wid >> 1, wy = wid & 1;
    int lr = lane & 15, lk = lane >> 4;
    int s = mb * 2 + wm;

    f32x4 zf = {0.f, 0.f, 0.f, 0.f};
    f32x4 acc[4][8];
    #pragma unroll
    for (int i = 0; i < 4; ++i)
        #pragma unroll
        for (int j = 0; j < 8; ++j) acc[i][j] = zf;

    // zero x-pads (slots 0 and 129) for 16 rows x 2 buffers, written once
    if (t < 64) {
        int buf = t >> 5, rr = (t & 31) >> 1, pos = (t & 1) ? 129 : 0;
        short8 z = {0, 0, 0, 0, 0, 0, 0, 0};
        *(short8*)&Bl[buf * BSZc + (rr * 130 + pos) * 8] = z;
    }

    auto STAGE = [&](int bufi, int kc) {
        #pragma unroll
        for (int i = 0; i < 8; ++i) {
            int run = wid * 8 + i;            // 0..31 = hy(4) x lk(4) x seg(2)
            int hy = run >> 3, slk = (run >> 1) & 3, seg = run & 1;
            int yy = ybase + hy - 1;
            int dst = bufi * BSZc + ((hy * 4 + slk) * 130 + 1 + seg * 64) * 8;
            if (yy < 0 || yy >= Hn) {
                short8 z = {0, 0, 0, 0, 0, 0, 0, 0};
                *(short8*)&Bl[dst + lane * 8] = z;
            } else {
                const u16* g = xTt + (((size_t)(b * 32 + kc * 4 + slk)) * Nn
                                      + yy * Wn + seg * 64 + lane) * 8;
                GLOAD_LDS16(g, &Bl[dst]);
            }
        }
    };

    STAGE(0, 0);
    __syncthreads();

    #pragma unroll 2
    for (int kc = 0; kc < 8; ++kc) {
        int cur = kc & 1;
        if (kc < 7) STAGE(cur ^ 1, kc + 1);
        int cb = cur * BSZc;
        int abase = ((kc * 4 + s) * 4) * 512 + lane * 8;
        #pragma unroll
        for (int dy = 0; dy < 3; ++dy) {
            int rbase = cb + ((wy + dy) * 4 + lk) * 130 * 8;
            #pragma unroll
            for (int dx = 0; dx < 3; ++dx) {
                short8 bf[8];
                #pragma unroll
                for (int nf = 0; nf < 8; ++nf)
                    bf[nf] = *(const short8*)&Bl[rbase + (nf * 16 + lr + dx) * 8];
                const u16* ap = wallp + (dy * 3 + dx) * 65536 + abase;
                #pragma unroll
                for (int mf = 0; mf < 4; ++mf) {
                    short8 af = *(const short8*)&ap[mf * 512];
                    #pragma unroll
                    for (int nf = 0; nf < 8; ++nf)
                        acc[mf][nf] = __builtin_amdgcn_mfma_f32_16x16x32_bf16(af, bf[nf], acc[mf][nf], 0, 0, 0);
                }
            }
        }
        __syncthreads();
    }

    float g = gamma[0];
    int nrow = (ybase + wy) * Wn;
    float nr8[8];
    #pragma unroll
    for (int nf = 0; nf < 8; ++nf)
        nr8[nf] = nrm[b * Nn + nrow + nf * 16 + lr];
    #pragma unroll
    for (int mf = 0; mf < 4; ++mf) {
        #pragma unroll
        for (int r = 0; r < 4; ++r) {
            int o = mb * 128 + wm * 64 + mf * 16 + lk * 4 + r;
            float es_o = esum[b * Cn + o];
            float bf_o = bfused[o];
            size_t rowbase = ((size_t)(b * Cn + o)) * Nn + nrow;
            #pragma unroll
            for (int nf = 0; nf < 8; ++nf) {
                size_t idx = rowbase + nf * 16 + lr;
                float conv = acc[mf][nf][r] + bf_o;
                float att = es_o * bf2f(kv[idx]) * nr8[nf];
                out[idx] = x[idx] + g * (att + conv);
            }
        }
    }
}

extern "C" void kernel_launch(void* const* d_in, const int* in_sizes, int n_in,
                              void* d_out, int out_size, void* d_ws, size_t ws_size,
                              hipStream_t stream)
{
    const float* x1  = (const float*)d_in[0];
    const float* x2  = (const float*)d_in[1];
    const float* wq1 = (const float*)d_in[2];
    const float* bq1 = (const float*)d_in[3];
    const float* wk1 = (const float*)d_in[4];
    const float* bk1 = (const float*)d_in[5];
    const float* wv1 = (const float*)d_in[6];
    const float* bv1 = (const float*)d_in[7];
    const float* wq2 = (const float*)d_in[8];
    const float* bq2 = (const float*)d_in[9];
    const float* wk2 = (const float*)d_in[10];
    const float* bk2 = (const float*)d_in[11];
    const float* wv2 = (const float*)d_in[12];
    const float* bv2 = (const float*)d_in[13];
    const float* wd1 = (const float*)d_in[14];
    const float* bd1 = (const float*)d_in[15];
    const float* wd3 = (const float*)d_in[16];
    const float* bd3 = (const float*)d_in[17];
    const float* gamma1 = (const float*)d_in[18];
    const float* gamma2 = (const float*)d_in[19];

    char* ws = (char*)d_ws;
    size_t off = 0;
    auto alloc = [&](size_t bytes) { char* p = ws + off; off += (bytes + 255) & ~(size_t)255; return p; };

    u16* xT1   = (u16*)alloc((size_t)Bn * Nn * Cn * 2);
    u16* xT2   = (u16*)alloc((size_t)Bn * Nn * Cn * 2);
    u16* k1    = (u16*)alloc((size_t)Bn * Cn * Nn * 2);
    u16* k2    = (u16*)alloc((size_t)Bn * Cn * Nn * 2);
    u16* kv2   = (u16*)alloc((size_t)Bn * Cn * Nn * 2);
    u16* wallp = (u16*)alloc((size_t)9 * 65536 * 2);
    u16* wq1p  = (u16*)alloc(65536 * 2);
    u16* wk1p  = (u16*)alloc(65536 * 2);
    u16* wv1p  = (u16*)alloc(65536 * 2);
    u16* wq2p  = (u16*)alloc(65536 * 2);
    u16* wk2p  = (u16*)alloc(65536 * 2);
    u16* wv2p  = (u16*)alloc(65536 * 2);
    float* qsum1 = (float*)alloc(Bn * Nn * 4);
    float* qsum2 = (float*)alloc(Bn * Nn * 4);
    float* esum1 = (float*)alloc(Bn * Cn * 4);
    float* esum2 = (float*)alloc(Bn * Cn * 4);
    float* norm1 = (float*)alloc(Bn * Nn * 4);
    float* norm2 = (float*)alloc(Bn * Nn * 4);
    float* bfused = (float*)alloc(Cn * 4);

    float* out1 = (float*)d_out;
    float* out2 = out1 + (size_t)Bn * Cn * Nn;
    // kv1 parks in the out2 half of d_out; conv_att1 consumes it before conv_att2 writes out2
    u16* kv1 = (u16*)out2;

    hipMemsetAsync(qsum1, 0, Bn * Nn * 4, stream);
    hipMemsetAsync(qsum2, 0, Bn * Nn * 4, stream);

    prep_kernel<<<dim3(256), dim3(256), 0, stream>>>(wq1, wk1, wv1, wq2, wk2, wv2, wd1, wd3,
                                                     bd1, bd3, wq1p, wk1p, wv1p,
                                                     wq2p, wk2p, wv2p, wallp, bfused);
    transpose_kernel<<<dim3(256, 4, 4), 256, 0, stream>>>(x1, xT1);
    transpose_kernel<<<dim3(256, 4, 4), 256, 0, stream>>>(x2, xT2);
    qkv_kernel<<<dim3(128, 2, 4), 256, 0, stream>>>(xT1, wq1p, wk1p, wv1p, bq1, bk1, bv1,
                                                    k1, kv1, qsum1);
    qkv_kernel<<<dim3(128, 2, 4), 256, 0, stream>>>(xT2, wq2p, wk2p, wv2p, bq2, bk2, bv2,
                                                    k2, kv2, qsum2);
    esum_kernel<<<dim3(256, 4), 256, 0, stream>>>(k2, qsum1, esum1);
    esum_kernel<<<dim3(256, 4), 256, 0, stream>>>(k1, qsum2, esum2);
    norm_kernel<<<dim3(16, 4), 256, 0, stream>>>(k2, esum1, norm1);
    norm_kernel<<<dim3(16, 4), 256, 0, stream>>>(k1, esum2, norm2);
    conv_att_kernel<<<dim3(2, 64, 4), 256, 0, stream>>>(x1, xT1, wallp, bfused, kv1,
                                                        esum1, norm1, gamma1, out1);
    conv_att_kernel<<<dim3(2, 64, 4), 256, 0, stream>>>(x2, xT2, wallp, bfused, kv2,
                                                        esum2, norm2, gamma2, out2);
}

// Round 5
// 390.893 us; speedup vs baseline: 1.2127x; 1.2127x over previous
//
#include <hip/hip_runtime.h>
#include <stdint.h>

#define Bn 4
#define Cn 256
#define Hn 128
#define Wn 128
#define Nn 16384
#define EPSn 1e-10f

typedef unsigned short u16;
typedef __attribute__((ext_vector_type(8))) short short8;
typedef __attribute__((ext_vector_type(4))) short short4v;
typedef __attribute__((ext_vector_type(4))) float f32x4;

#define GLOAD_LDS16(g, l)                                                        \
    __builtin_amdgcn_global_load_lds(                                            \
        (const __attribute__((address_space(1))) unsigned int*)(const void*)(g), \
        (__attribute__((address_space(3))) unsigned int*)(void*)(l), 16, 0, 0)

__device__ __forceinline__ float bf2f(u16 u) {
    union { float f; uint32_t i; } v; v.i = ((uint32_t)u) << 16; return v.f;
}
__device__ __forceinline__ u16 f2bf(float f) {
    union { float f; uint32_t i; } v; v.f = f;
    uint32_t r = v.i + 0x7FFFu + ((v.i >> 16) & 1u);
    return (u16)(r >> 16);
}
__device__ __forceinline__ float delu_f(float x) {
    return x >= 0.f ? fmaf(10.f, x, 1.f) : __expf(10.f * x);
}

// ---------------- prep: pack all weights into MFMA-fragment order ----------------
// poff = ((kc*4+s)*4+mf)*512 + (lk*16+lr)*8 + j   -> per-(kc,s,mf) contiguous 1KB block
// conv weights per image: center tap gets + wd1 + (1/gamma) * I  (residual fold)
__global__ void prep_kernel(const float* __restrict__ wq1, const float* __restrict__ wk1,
                            const float* __restrict__ wv1,
                            const float* __restrict__ wq2, const float* __restrict__ wk2,
                            const float* __restrict__ wv2,
                            const float* __restrict__ wd1, const float* __restrict__ wd3,
                            const float* __restrict__ bd1, const float* __restrict__ bd3,
                            const float* __restrict__ gamma1, const float* __restrict__ gamma2,
                            u16* __restrict__ wq1p, u16* __restrict__ wk1p, u16* __restrict__ wv1p,
                            u16* __restrict__ wq2p, u16* __restrict__ wk2p, u16* __restrict__ wv2p,
                            u16* __restrict__ wallp1, u16* __restrict__ wallp2,
                            float* __restrict__ bfused)
{
    int idx = blockIdx.x * 256 + threadIdx.x;   // o*256 + c
    int o = idx >> 8, c = idx & 255;
    if (idx < 256) bfused[idx] = bd1[idx] + bd3[idx];
    int s = o >> 6, mf = (o >> 4) & 3, lr = o & 15;
    int kc = c >> 5, lk = (c >> 3) & 3, j = c & 7;
    int poff = ((kc * 4 + s) * 4 + mf) * 512 + (lk * 16 + lr) * 8 + j;
    wq1p[poff] = f2bf(wq1[idx]);
    wk1p[poff] = f2bf(wk1[idx]);
    wv1p[poff] = f2bf(wv1[idx]);
    wq2p[poff] = f2bf(wq2[idx]);
    wk2p[poff] = f2bf(wk2[idx]);
    wv2p[poff] = f2bf(wv2[idx]);
    float wd1v = wd1[idx];
    float inv1 = 1.f / gamma1[0];
    float inv2 = 1.f / gamma2[0];
    float diag = (o == c) ? 1.f : 0.f;
    #pragma unroll
    for (int tap = 0; tap < 9; ++tap) {
        float w = wd3[idx * 9 + tap] + (tap == 4 ? wd1v : 0.f);
        wallp1[tap * 65536 + poff] = f2bf(w + (tap == 4 ? diag * inv1 : 0.f));
        wallp2[tap * 65536 + poff] = f2bf(w + (tap == 4 ? diag * inv2 : 0.f));
    }
}

// ---------------- transpose: x (B,C,N) f32 -> xT (B,N,C) bf16 ----------------
__global__ void transpose_kernel(const float* __restrict__ x, u16* __restrict__ xT)
{
    __shared__ __align__(16) u16 tl[64][72];
    int t = threadIdx.x;
    int n0 = blockIdx.x * 64, c0 = blockIdx.y * 64, b = blockIdx.z;
    int cl = t >> 4, nl = (t & 15) * 4;
    #pragma unroll
    for (int pc = 0; pc < 4; ++pc) {
        int c = pc * 16 + cl;
        float4 v = *(const float4*)&x[((size_t)(b * Cn + c0 + c)) * Nn + n0 + nl];
        tl[nl + 0][c] = f2bf(v.x);
        tl[nl + 1][c] = f2bf(v.y);
        tl[nl + 2][c] = f2bf(v.z);
        tl[nl + 3][c] = f2bf(v.w);
    }
    __syncthreads();
    #pragma unroll
    for (int ps = 0; ps < 2; ++ps) {
        int id = ps * 256 + t;
        int nr = id >> 3, cc = (id & 7) * 8;
        short8 v = *(const short8*)&tl[nr][cc];
        *(short8*)&xT[((size_t)(b * Nn + n0 + nr)) * 256 + c0 + cc] = v;
    }
}

// ---------------- fused Q+K+V projection GEMM ----------------
__global__ __launch_bounds__(256, 2) void qkv_kernel(
    const u16* __restrict__ xT,
    const u16* __restrict__ wqp, const u16* __restrict__ wkp, const u16* __restrict__ wvp,
    const float* __restrict__ bq, const float* __restrict__ bk, const float* __restrict__ bv,
    u16* __restrict__ kout, u16* __restrict__ kvout, float* __restrict__ qsum)
{
    __shared__ __align__(16) u16 Bt[2 * 4096];   // [buf][col128][ch32]
    int t = threadIdx.x;
    int nb = blockIdx.x, mb = blockIdx.y, b = blockIdx.z;
    int lane = t & 63, wid = t >> 6;
    int wm = wid >> 1, wn = wid & 1;
    int lr = lane & 15, lk = lane >> 4;
    int s = mb * 2 + wm;

    f32x4 zf = {0.f, 0.f, 0.f, 0.f};
    f32x4 accq[4][4], acck[4][4], accv[4][4];
    #pragma unroll
    for (int i = 0; i < 4; ++i)
        #pragma unroll
        for (int j = 0; j < 4; ++j) { accq[i][j] = zf; acck[i][j] = zf; accv[i][j] = zf; }

    int colp = lane >> 2, chp = (lane & 3) * 8;
    auto STAGE = [&](int bufi, int kc) {
        #pragma unroll
        for (int i = 0; i < 2; ++i) {
            int col0 = (wid * 2 + i) * 16;
            const u16* g = xT + ((size_t)(b * Nn + nb * 128 + col0 + colp)) * 256 + kc * 32 + chp;
            GLOAD_LDS16(g, &Bt[bufi * 4096 + col0 * 32]);
        }
    };

    STAGE(0, 0);
    __syncthreads();

    #pragma unroll 2
    for (int kc = 0; kc < 8; ++kc) {
        int cur = kc & 1;
        if (kc < 7) STAGE(cur ^ 1, kc + 1);
        int abase = ((kc * 4 + s) * 4) * 512 + lane * 8;
        short8 bf[4];
        #pragma unroll
        for (int nf = 0; nf < 4; ++nf)
            bf[nf] = *(const short8*)&Bt[cur * 4096 + (wn * 64 + nf * 16 + lr) * 32 + lk * 8];
        #pragma unroll
        for (int mf = 0; mf < 4; ++mf) {
            short8 aq = *(const short8*)&wqp[abase + mf * 512];
            short8 ak = *(const short8*)&wkp[abase + mf * 512];
            short8 av = *(const short8*)&wvp[abase + mf * 512];
            #pragma unroll
            for (int nf = 0; nf < 4; ++nf) {
                accq[mf][nf] = __builtin_amdgcn_mfma_f32_16x16x32_bf16(aq, bf[nf], accq[mf][nf], 0, 0, 0);
                acck[mf][nf] = __builtin_amdgcn_mfma_f32_16x16x32_bf16(ak, bf[nf], acck[mf][nf], 0, 0, 0);
                accv[mf][nf] = __builtin_amdgcn_mfma_f32_16x16x32_bf16(av, bf[nf], accv[mf][nf], 0, 0, 0);
            }
        }
        __syncthreads();
    }

    float qs[4] = {0.f, 0.f, 0.f, 0.f};
    #pragma unroll
    for (int mf = 0; mf < 4; ++mf) {
        #pragma unroll
        for (int r = 0; r < 4; ++r) {
            int o = mb * 128 + wm * 64 + mf * 16 + lk * 4 + r;
            float bqv = bq[o], bkv = bk[o], bvv = bv[o];
            #pragma unroll
            for (int nf = 0; nf < 4; ++nf) {
                int n = nb * 128 + wn * 64 + nf * 16 + lr;
                size_t idx = ((size_t)(b * Cn + o)) * Nn + n;
                float qv = delu_f(accq[mf][nf][r] + bqv);
                qs[nf] += qv;
                float kk = delu_f(acck[mf][nf][r] + bkv);
                kout[idx] = f2bf(kk);
                float vv = accv[mf][nf][r] + bvv;
                kvout[idx] = f2bf(kk * vv);
            }
        }
    }
    #pragma unroll
    for (int nf = 0; nf < 4; ++nf) {
        float sgl = qs[nf];
        sgl += __shfl_xor(sgl, 16);
        sgl += __shfl_xor(sgl, 32);
        if (lk == 0)
            atomicAdd(&qsum[b * Nn + nb * 128 + wn * 64 + nf * 16 + lr], sgl);
    }
}

// ---------------- esum[b,c] = sum_n k[b,c,n] * qsum[b,n] ----------------
__global__ void esum_kernel(const u16* __restrict__ k, const float* __restrict__ qsum,
                            float* __restrict__ esum)
{
    int c = blockIdx.x, b = blockIdx.y, t = threadIdx.x;
    const u16* kr = k + ((size_t)(b * Cn + c)) * Nn;
    const float* qr = qsum + b * Nn;
    float s = 0.f;
    for (int i = t * 8; i < Nn; i += 2048) {
        short8 kv = *(const short8*)&kr[i];
        #pragma unroll
        for (int j = 0; j < 8; ++j) s = fmaf(bf2f((u16)kv[j]), qr[i + j], s);
    }
    #pragma unroll
    for (int m = 32; m; m >>= 1) s += __shfl_xor(s, m);
    __shared__ float red[4];
    if ((t & 63) == 0) red[t >> 6] = s;
    __syncthreads();
    if (t == 0) esum[b * Cn + c] = red[0] + red[1] + red[2] + red[3];
}

// ---------------- norm[b,n] = 1/(sum_c esum[b,c]*k[b,c,n] + eps) ----------------
// 256 blocks (full GPU), one n per thread, coalesced 128B/wave loads
__global__ void norm_kernel(const u16* __restrict__ k, const float* __restrict__ esum,
                            float* __restrict__ nrm)
{
    __shared__ float es[256];
    int t = threadIdx.x, b = blockIdx.y;
    es[t] = esum[b * Cn + t];
    __syncthreads();
    int n = blockIdx.x * 256 + t;
    const u16* kb = k + (size_t)b * Cn * Nn + n;
    float a = 0.f;
    #pragma unroll 8
    for (int c = 0; c < 256; ++c)
        a = fmaf(es[c], bf2f(kb[(size_t)c * Nn]), a);
    nrm[b * Nn + n] = 1.f / (a + EPSn);
}

// ---------------- pass 2: halo-GEMM conv3x3(+1x1+residual) + att ----------------
// block: 128 out-ch x 256 px (2 y-rows). halo: [4 rows][130 x][32 ch], double buffered.
#define BROW 130
#define BSZ  (4 * BROW * 32)          // 16640 u16 per buffer

__global__ __launch_bounds__(256, 2) void conv_att_kernel(
    const u16* __restrict__ xT,
    const u16* __restrict__ wallp, const float* __restrict__ bfused,
    const u16* __restrict__ kv, const float* __restrict__ esum,
    const float* __restrict__ nrm, const float* __restrict__ gamma,
    float* __restrict__ out)
{
    __shared__ __align__(16) u16 Bl[2 * BSZ];    // 66,560 B
    int t = threadIdx.x;
    // bijective XCD swizzle: 512 wgs, 64 contiguous (b,yp,mb) per XCD
    int lin = (blockIdx.z * 64 + blockIdx.y) * 2 + blockIdx.x;
    int wg = (lin & 7) * 64 + (lin >> 3);
    int mb = wg & 1, yp = (wg >> 1) & 63, b = wg >> 7;
    int ybase = yp * 2;
    int lane = t & 63, wid = t >> 6;
    int wm = wid >> 1, wy = wid & 1;
    int lr = lane & 15, lk = lane >> 4;
    int s = mb * 2 + wm;

    f32x4 zf = {0.f, 0.f, 0.f, 0.f};
    f32x4 acc[4][8];
    #pragma unroll
    for (int i = 0; i < 4; ++i)
        #pragma unroll
        for (int j = 0; j < 8; ++j) acc[i][j] = zf;

    // zero x-pads (pos 0 and 129) for 4 rows x 2 buffers, written once
    if (t < 64) {
        int buf = t >> 5, rr = (t >> 3) & 3, pos = (t & 4) ? 129 : 0, chq = t & 3;
        short8 z = {0, 0, 0, 0, 0, 0, 0, 0};
        *(short8*)&Bl[buf * BSZ + (rr * BROW + pos) * 32 + chq * 8] = z;
    }

    int colp = lane >> 2, chp = (lane & 3) * 8;
    auto STAGE = [&](int bufi, int kc) {
        #pragma unroll
        for (int i = 0; i < 8; ++i) {
            int ch = wid * 8 + i;         // 0..31 = hy(4) x seg(8)
            int hy = ch >> 3, sx = ch & 7;
            int yy = ybase + hy - 1;
            int base = bufi * BSZ + (hy * BROW + 1 + sx * 16) * 32;
            if (yy < 0 || yy >= Hn) {
                short8 z = {0, 0, 0, 0, 0, 0, 0, 0};
                *(short8*)&Bl[base + lane * 8] = z;
            } else {
                const u16* g = xT + ((size_t)(b * Nn + yy * Wn + sx * 16 + colp)) * 256
                                  + kc * 32 + chp;
                GLOAD_LDS16(g, &Bl[base]);
            }
        }
    };

    STAGE(0, 0);
    __syncthreads();

    #pragma unroll 2
    for (int kc = 0; kc < 8; ++kc) {
        int cur = kc & 1;
        if (kc < 7) STAGE(cur ^ 1, kc + 1);
        int cb = cur * BSZ;
        int abase = ((kc * 4 + s) * 4) * 512 + lane * 8;
        #pragma unroll
        for (int dy = 0; dy < 3; ++dy) {
            #pragma unroll
            for (int dx = 0; dx < 3; ++dx) {
                short8 bf[8];
                #pragma unroll
                for (int nf = 0; nf < 8; ++nf)
                    bf[nf] = *(const short8*)&Bl[cb + ((wy + dy) * BROW + nf * 16 + lr + dx) * 32 + lk * 8];
                const u16* ap = wallp + (dy * 3 + dx) * 65536 + abase;
                #pragma unroll
                for (int mf = 0; mf < 4; ++mf) {
                    short8 af = *(const short8*)&ap[mf * 512];
                    #pragma unroll
                    for (int nf = 0; nf < 8; ++nf)
                        acc[mf][nf] = __builtin_amdgcn_mfma_f32_16x16x32_bf16(af, bf[nf], acc[mf][nf], 0, 0, 0);
                }
            }
        }
        __syncthreads();
    }

    float g = gamma[0];
    int nrow = (ybase + wy) * Wn;
    float nr8[8];
    #pragma unroll
    for (int nf = 0; nf < 8; ++nf)
        nr8[nf] = nrm[b * Nn + nrow + nf * 16 + lr];
    #pragma unroll
    for (int mf = 0; mf < 4; ++mf) {
        #pragma unroll
        for (int r = 0; r < 4; ++r) {
            int o = mb * 128 + wm * 64 + mf * 16 + lk * 4 + r;
            float es_o = esum[b * Cn + o];
            float bf_o = bfused[o];
            size_t rowbase = ((size_t)(b * Cn + o)) * Nn + nrow;
            #pragma unroll
            for (int nf = 0; nf < 8; ++nf) {
                size_t idx = rowbase + nf * 16 + lr;
                float att = es_o * bf2f(kv[idx]) * nr8[nf];
                out[idx] = g * (acc[mf][nf][r] + bf_o + att);
            }
        }
    }
}

extern "C" void kernel_launch(void* const* d_in, const int* in_sizes, int n_in,
                              void* d_out, int out_size, void* d_ws, size_t ws_size,
                              hipStream_t stream)
{
    const float* x1  = (const float*)d_in[0];
    const float* x2  = (const float*)d_in[1];
    const float* wq1 = (const float*)d_in[2];
    const float* bq1 = (const float*)d_in[3];
    const float* wk1 = (const float*)d_in[4];
    const float* bk1 = (const float*)d_in[5];
    const float* wv1 = (const float*)d_in[6];
    const float* bv1 = (const float*)d_in[7];
    const float* wq2 = (const float*)d_in[8];
    const float* bq2 = (const float*)d_in[9];
    const float* wk2 = (const float*)d_in[10];
    const float* bk2 = (const float*)d_in[11];
    const float* wv2 = (const float*)d_in[12];
    const float* bv2 = (const float*)d_in[13];
    const float* wd1 = (const float*)d_in[14];
    const float* bd1 = (const float*)d_in[15];
    const float* wd3 = (const float*)d_in[16];
    const float* bd3 = (const float*)d_in[17];
    const float* gamma1 = (const float*)d_in[18];
    const float* gamma2 = (const float*)d_in[19];

    char* ws = (char*)d_ws;
    size_t off = 0;
    auto alloc = [&](size_t bytes) { char* p = ws + off; off += (bytes + 255) & ~(size_t)255; return p; };

    u16* xT1    = (u16*)alloc((size_t)Bn * Nn * Cn * 2);
    u16* xT2    = (u16*)alloc((size_t)Bn * Nn * Cn * 2);
    u16* k1     = (u16*)alloc((size_t)Bn * Cn * Nn * 2);
    u16* k2     = (u16*)alloc((size_t)Bn * Cn * Nn * 2);
    u16* kv2    = (u16*)alloc((size_t)Bn * Cn * Nn * 2);
    u16* wallp1 = (u16*)alloc((size_t)9 * 65536 * 2);
    u16* wallp2 = (u16*)alloc((size_t)9 * 65536 * 2);
    u16* wq1p   = (u16*)alloc(65536 * 2);
    u16* wk1p   = (u16*)alloc(65536 * 2);
    u16* wv1p   = (u16*)alloc(65536 * 2);
    u16* wq2p   = (u16*)alloc(65536 * 2);
    u16* wk2p   = (u16*)alloc(65536 * 2);
    u16* wv2p   = (u16*)alloc(65536 * 2);
    float* qsum1 = (float*)alloc(Bn * Nn * 4);
    float* qsum2 = (float*)alloc(Bn * Nn * 4);
    float* esum1 = (float*)alloc(Bn * Cn * 4);
    float* esum2 = (float*)alloc(Bn * Cn * 4);
    float* norm1 = (float*)alloc(Bn * Nn * 4);
    float* norm2 = (float*)alloc(Bn * Nn * 4);
    float* bfused = (float*)alloc(Cn * 4);

    float* out1 = (float*)d_out;
    float* out2 = out1 + (size_t)Bn * Cn * Nn;
    // kv1 parks in the out2 half of d_out; conv_att1 consumes it before conv_att2 writes out2
    u16* kv1 = (u16*)out2;

    hipMemsetAsync(qsum1, 0, Bn * Nn * 4, stream);
    hipMemsetAsync(qsum2, 0, Bn * Nn * 4, stream);

    prep_kernel<<<dim3(256), dim3(256), 0, stream>>>(wq1, wk1, wv1, wq2, wk2, wv2, wd1, wd3,
                                                     bd1, bd3, gamma1, gamma2,
                                                     wq1p, wk1p, wv1p, wq2p, wk2p, wv2p,
                                                     wallp1, wallp2, bfused);
    transpose_kernel<<<dim3(256, 4, 4), 256, 0, stream>>>(x1, xT1);
    transpose_kernel<<<dim3(256, 4, 4), 256, 0, stream>>>(x2, xT2);
    qkv_kernel<<<dim3(128, 2, 4), 256, 0, stream>>>(xT1, wq1p, wk1p, wv1p, bq1, bk1, bv1,
                                                    k1, kv1, qsum1);
    qkv_kernel<<<dim3(128, 2, 4), 256, 0, stream>>>(xT2, wq2p, wk2p, wv2p, bq2, bk2, bv2,
                                                    k2, kv2, qsum2);
    esum_kernel<<<dim3(256, 4), 256, 0, stream>>>(k2, qsum1, esum1);
    esum_kernel<<<dim3(256, 4), 256, 0, stream>>>(k1, qsum2, esum2);
    norm_kernel<<<dim3(64, 4), 256, 0, stream>>>(k2, esum1, norm1);
    norm_kernel<<<dim3(64, 4), 256, 0, stream>>>(k1, esum2, norm2);
    conv_att_kernel<<<dim3(2, 64, 4), 256, 0, stream>>>(xT1, wallp1, bfused, kv1,
                                                        esum1, norm1, gamma1, out1);
    conv_att_kernel<<<dim3(2, 64, 4), 256, 0, stream>>>(xT2, wallp2, bfused, kv2,
                                                        esum2, norm2, gamma2, out2);
}